// Round 6
// baseline (255.322 us; speedup 1.0000x reference)
//
#include <hip/hip_runtime.h>
#include <hip/hip_bf16.h>

typedef __hip_bfloat16 bf16;
typedef unsigned short ushort;

#define NN 100000
#define NE 1600000
#define NBKT 391      // ceil(NN/256) buckets of 256 dst nodes
#define BCAP 4608     // per-bucket capacity (mean 4092, sd 64, +8 sigma)
#define EPB 4096      // edges per count/place block
#define NP1 391       // ceil(NE/EPB)
#define NMT 6250      // NN/16 M-tiles for the MFMA GEMM

typedef __attribute__((ext_vector_type(8))) short s8v;   // 8 bf16 (4 VGPRs)
typedef __attribute__((ext_vector_type(4))) float f4v;   // MFMA C/D
typedef __attribute__((ext_vector_type(2))) float f2v;   // packed f32 (v_pk_add_f32)

// ---- flag-dispatched load/store: flag==1 -> f32 storage, 0 -> bf16 -------
__device__ __forceinline__ float ldf(const void* p, int i, int f32) {
    return f32 ? ((const float*)p)[i] : __bfloat162float(((const bf16*)p)[i]);
}
__device__ __forceinline__ void stf(void* p, int i, int f32, float v) {
    if (f32) ((float*)p)[i] = v;
    else     ((bf16*)p)[i] = __float2bfloat16(v);
}

// round-to-nearest-even float -> bf16 bits, and back
__device__ __forceinline__ ushort f2b(float f) {
    unsigned u = __builtin_bit_cast(unsigned, f);
    u += 0x7FFF + ((u >> 16) & 1);
    return (ushort)(u >> 16);
}
__device__ __forceinline__ float b2f(ushort h) {
    unsigned u = ((unsigned)h) << 16;
    return __builtin_bit_cast(float, u);
}
// bf16x2 dword -> two f32 (lo = bits<<16, hi = bits&0xffff0000)
__device__ __forceinline__ float blo(unsigned u) {
    return __builtin_bit_cast(float, u << 16);
}
__device__ __forceinline__ float bhi(unsigned u) {
    return __builtin_bit_cast(float, u & 0xffff0000u);
}
// unpack bf16x2 dword into a packed f32 pair (consumed by v_pk_add_f32)
__device__ __forceinline__ f2v up2(unsigned u) {
    f2v r; r.x = blo(u); r.y = bhi(u); return r;
}

__global__ void k_sentinel(unsigned* out) {
    if (threadIdx.x == 0 && blockIdx.x == 0) out[0] = 0x461C461Cu;
}

// ---------------- CSR build A: per-block bucket counts + dtype detect ------
__global__ void k_cnt(const unsigned* __restrict__ x, int* __restrict__ flag,
                      const int* __restrict__ dst, int* __restrict__ cnt) {
    __shared__ int hist[NBKT];
    int b = blockIdx.x, t = threadIdx.x;
    for (int i = t; i < NBKT; i += 256) hist[i] = 0;
    __syncthreads();
    int e0 = b * EPB;
#pragma unroll
    for (int k = 0; k < EPB; k += 256) {
        int e = e0 + k + t;
        if (e < NE) atomicAdd(&hist[dst[e] >> 8], 1);
    }
    __syncthreads();
    for (int i = t; i < NBKT; i += 256) cnt[b * NBKT + i] = hist[i];
    if (b == 0) {
        // dtype detect on first 2048 words of x (merged launch; reuses hist)
        int c = 0;
        for (int i = t; i < 2048; i += 256) {
            unsigned e7 = (x[i] >> 8) & 0x7F;
            c += (e7 >= 60 && e7 <= 66) ? 1 : 0;
        }
        __syncthreads();
        hist[t] = c;
        __syncthreads();
        for (int s = 128; s > 0; s >>= 1) {
            if (t < s) hist[t] += hist[t + s];
            __syncthreads();
        }
        if (t == 0) *flag = (hist[0] >= 1024) ? 0 : 1;  // 1 = float32 tensors
    }
}

// ---------------- CSR build B: per-bucket scan over blocks -----------------
// Block k reads column cnt[.][k] (strided reads, L2/L3-cached), scans,
// writes exclusive prefixes COALESCED to prefT[k][.] and the bucket total.
__global__ void k_colscan(const int* __restrict__ cnt, int* __restrict__ prefT,
                          int* __restrict__ btot) {
    __shared__ int s[512];
    int k = blockIdx.x, t = threadIdx.x;
    int v = (t < NP1) ? cnt[t * NBKT + k] : 0;
    s[t] = v;
    __syncthreads();
    for (int d = 1; d < 512; d <<= 1) {
        int add = (t >= d) ? s[t - d] : 0;
        __syncthreads();
        s[t] += add;
        __syncthreads();
    }
    if (t < NP1) prefT[k * NP1 + t] = s[t] - v;   // exclusive over blocks
    if (t == 511) btot[k] = s[511];
}

// ---------------- CSR build C: deterministic place into buckets ------------
// No global atomics: slot = prefT[k][b] + LDS cursor. Writes are ~10-word
// contiguous runs per bucket (vs 16x-amplified random 4B stores in r3).
__global__ void k_place(const int* __restrict__ src, const int* __restrict__ dst,
                        const int* __restrict__ prefT, unsigned* __restrict__ bbuf) {
    __shared__ int base[NBKT];
    __shared__ int lcur[NBKT];
    int b = blockIdx.x, t = threadIdx.x;
    for (int i = t; i < NBKT; i += 256) {
        base[i] = prefT[i * NP1 + b];
        lcur[i] = 0;
    }
    __syncthreads();
    int e0 = b * EPB;
#pragma unroll
    for (int k = 0; k < EPB; k += 256) {
        int e = e0 + k + t;
        if (e < NE) {
            int d = dst[e];
            int kb = d >> 8;
            int lp = atomicAdd(&lcur[kb], 1);
            bbuf[kb * BCAP + base[kb] + lp] = ((unsigned)src[e] << 8) | (unsigned)(d & 255);
        }
    }
}

// ---------------- CSR build D: LDS counting-sort per bucket ----------------
// Emits csr_off (BYTE offsets src*128) coalesced, plus rowptr and dis.
// Bucket base g0 = sum(btot[0..b-1]) is computed locally (replaces the
// former single-block scan kernel -- one fewer launch).
__global__ void k_pass2(const unsigned* __restrict__ bbuf, const int* __restrict__ btot,
                        int* __restrict__ rowptr, float* __restrict__ dis,
                        int* __restrict__ csr_off) {
    __shared__ unsigned vals[BCAP];
    __shared__ int lout[BCAP];
    __shared__ int fh[256], fx[256], fc[256];
    int b = blockIdx.x, t = threadIdx.x;
    // ---- local bucket base: reduce btot[0..b-1] (<=2 loads/thread) ----
    int part = 0;
    for (int i = t; i < b; i += 256) part += btot[i];
    fh[t] = part;
    __syncthreads();
    for (int s = 128; s > 0; s >>= 1) {
        if (t < s) fh[t] += fh[t + s];
        __syncthreads();
    }
    int g0 = fh[0];
    int cntb = btot[b];
    if (b == 0 && t == 0) rowptr[NN] = NE;
    __syncthreads();
    const unsigned* in = bbuf + b * BCAP;
    fh[t] = 0;
    __syncthreads();
    for (int i = t; i < cntb; i += 256) {
        unsigned v = in[i];
        vals[i] = v;
        atomicAdd(&fh[v & 255], 1);
    }
    __syncthreads();
    fx[t] = fh[t];
    __syncthreads();
    for (int d = 1; d < 256; d <<= 1) {
        int add = (t >= d) ? fx[t - d] : 0;
        __syncthreads();
        fx[t] += add;
        __syncthreads();
    }
    int n = b * 256 + t;
    int ex = fx[t] - fh[t];     // exclusive within bucket
    fc[t] = ex;
    if (n < NN) {
        rowptr[n] = g0 + ex;
        dis[n] = rsqrtf(1.0f + (float)fh[t]);
    }
    __syncthreads();
    for (int i = t; i < cntb; i += 256) {
        unsigned v = vals[i];
        int p = atomicAdd(&fc[v & 255], 1);
        lout[p] = (int)((v >> 8) << 7);   // src*128 = byte offset of bf16 row
    }
    __syncthreads();
    for (int i = t; i < cntb; i += 256) csr_off[g0 + i] = lout[i];
}

// ---------------- MFMA GEMM: C[N,64] = dis[row] * (A[N,64] @ W[64,64]) ----
__global__ void __launch_bounds__(256) k_gemm_mfma(
        const void* __restrict__ A, int aBase, const void* __restrict__ W,
        bf16* __restrict__ C, const float* __restrict__ dis,
        const int* __restrict__ flag) {
    int f32 = *flag;
    int t = threadIdx.x;
    // zero pad row NN (the aggregate's ZOFF target) once per GEMM launch
    if (blockIdx.x == 0 && t < 64) ((ushort*)C)[NN * 64 + t] = 0;
    int lane = t & 63;
    int w = t >> 6;
    int m = lane & 15, q = lane >> 4;

    s8v bh[2][4], bl[2][4];
#pragma unroll
    for (int st = 0; st < 2; st++)
#pragma unroll
        for (int nt = 0; nt < 4; nt++)
#pragma unroll
            for (int j = 0; j < 8; j++) {
                int k = st * 32 + q * 8 + j;
                float wv = ldf(W, k * 64 + nt * 16 + m, f32);
                ushort h = f2b(wv);
                bh[st][nt][j] = (short)h;
                bl[st][nt][j] = (short)f2b(wv - b2f(h));
            }

    ushort* Cu = (ushort*)C;
    int gw = blockIdx.x * 4 + w;
    int nw = gridDim.x * 4;
    for (int mt = gw; mt < NMT; mt += nw) {
        int row = mt * 16 + m;
        s8v ah[2], al[2];
        if (f32) {
            const float* ap = (const float*)A + aBase + row * 64 + q * 8;
#pragma unroll
            for (int st = 0; st < 2; st++)
#pragma unroll
                for (int j = 0; j < 8; j++) {
                    float v = ap[st * 32 + j];
                    ushort h = f2b(v);
                    ah[st][j] = (short)h;
                    al[st][j] = (short)f2b(v - b2f(h));
                }
        } else {
            const short* ap = (const short*)A + aBase + row * 64 + q * 8;
            ah[0] = *(const s8v*)(ap);
            ah[1] = *(const s8v*)(ap + 32);
        }
        float dr[4];
#pragma unroll
        for (int r = 0; r < 4; r++) dr[r] = dis[mt * 16 + q * 4 + r];
#pragma unroll
        for (int nt = 0; nt < 4; nt++) {
            f4v acc = {0.f, 0.f, 0.f, 0.f};
#pragma unroll
            for (int st = 0; st < 2; st++)
                acc = __builtin_amdgcn_mfma_f32_16x16x32_bf16(ah[st], bh[st][nt], acc, 0, 0, 0);
            if (f32) {
#pragma unroll
                for (int st = 0; st < 2; st++) {
                    acc = __builtin_amdgcn_mfma_f32_16x16x32_bf16(ah[st], bl[st][nt], acc, 0, 0, 0);
                    acc = __builtin_amdgcn_mfma_f32_16x16x32_bf16(al[st], bh[st][nt], acc, 0, 0, 0);
                }
            }
            int col = nt * 16 + m;
#pragma unroll
            for (int r = 0; r < 4; r++) {
                int rr = mt * 16 + q * 4 + r;
                Cu[rr * 64 + col] = f2b(dr[r] * acc[r]);
            }
        }
    }
}

// ---------------- fused aggregate + bias + relu ---------------------------
// hs holds PRE-SCALED rows dis[s]*h[s] (bf16). One WAVE per NODE PAIR,
// persistent blocks. The r5 counters showed the kernel is bound by
// outstanding-L2-miss capacity (2.1 TB/s fill at 40% VALU, 65% occ), so this
// version doubles per-wave MLP: both nodes' 16-edge groups are interleaved,
// putting 8 independent 512B gathers in flight per iteration. Lanes: 4
// row-slots (q) x 16 feature-quads (m); gathers are uint2 (4 features)/lane.
// Full groups are branch-free; leftovers run singly; one combined guarded
// tail redirects dead slots to the (cached) zero row bufA[NN].
__global__ void __launch_bounds__(256, 8) k_aggregate(
        const bf16* __restrict__ hs, void* hout, int hoBase,
        const float* __restrict__ dis,
        const int* __restrict__ rowptr,
        const int* __restrict__ csr_off,
        const void* __restrict__ bias,
        const int* __restrict__ flag) {
    int f32 = *flag;
    int t = threadIdx.x;
    int l = t & 63;
    int q = l >> 4;           // row slot 0..3
    int m = l & 15;           // feature quad: features 4m..4m+3
    int fb = m * 8;           // byte offset of feature quad within 128B row
    const char* hb = (const char*)hs;
    float b0 = ldf(bias, m * 4 + 0, f32);
    float b1v = ldf(bias, m * 4 + 1, f32);
    float b2v = ldf(bias, m * 4 + 2, f32);
    float b3v = ldf(bias, m * 4 + 3, f32);
    const int Z = NN * 128;   // zero-row byte offset
    int wid = blockIdx.x * 4 + (t >> 6);
    int nwav = gridDim.x * 4;
    for (int p = wid; p < NN / 2; p += nwav) {
        int n0 = p * 2, n1 = n0 + 1;
        int r0 = rowptr[n0], r1 = rowptr[n0 + 1], r2 = rowptr[n1 + 1];
        int j0 = r0, e0 = r1, j1 = r1, e1 = r2;
        f2v a01 = {0.f, 0.f}, a23 = {0.f, 0.f};   // node n0
        f2v c01 = {0.f, 0.f}, c23 = {0.f, 0.f};   // node n1
        // paired full groups: 32 edges, 8 independent gathers in flight
        for (; j0 + 16 <= e0 && j1 + 16 <= e1; j0 += 16, j1 += 16) {
            int o0 = csr_off[j0 + q];
            int o1 = csr_off[j0 + 4 + q];
            int o2 = csr_off[j0 + 8 + q];
            int o3 = csr_off[j0 + 12 + q];
            int p0 = csr_off[j1 + q];
            int p1 = csr_off[j1 + 4 + q];
            int p2 = csr_off[j1 + 8 + q];
            int p3 = csr_off[j1 + 12 + q];
            uint2 v0 = *(const uint2*)(hb + o0 + fb);
            uint2 v1 = *(const uint2*)(hb + o1 + fb);
            uint2 v2 = *(const uint2*)(hb + o2 + fb);
            uint2 v3 = *(const uint2*)(hb + o3 + fb);
            uint2 w0 = *(const uint2*)(hb + p0 + fb);
            uint2 w1 = *(const uint2*)(hb + p1 + fb);
            uint2 w2 = *(const uint2*)(hb + p2 + fb);
            uint2 w3 = *(const uint2*)(hb + p3 + fb);
            a01 += up2(v0.x); a23 += up2(v0.y);
            a01 += up2(v1.x); a23 += up2(v1.y);
            a01 += up2(v2.x); a23 += up2(v2.y);
            a01 += up2(v3.x); a23 += up2(v3.y);
            c01 += up2(w0.x); c23 += up2(w0.y);
            c01 += up2(w1.x); c23 += up2(w1.y);
            c01 += up2(w2.x); c23 += up2(w2.y);
            c01 += up2(w3.x); c23 += up2(w3.y);
        }
        // leftover full groups, node n0
        for (; j0 + 16 <= e0; j0 += 16) {
            int o0 = csr_off[j0 + q];
            int o1 = csr_off[j0 + 4 + q];
            int o2 = csr_off[j0 + 8 + q];
            int o3 = csr_off[j0 + 12 + q];
            uint2 v0 = *(const uint2*)(hb + o0 + fb);
            uint2 v1 = *(const uint2*)(hb + o1 + fb);
            uint2 v2 = *(const uint2*)(hb + o2 + fb);
            uint2 v3 = *(const uint2*)(hb + o3 + fb);
            a01 += up2(v0.x); a23 += up2(v0.y);
            a01 += up2(v1.x); a23 += up2(v1.y);
            a01 += up2(v2.x); a23 += up2(v2.y);
            a01 += up2(v3.x); a23 += up2(v3.y);
        }
        // leftover full groups, node n1
        for (; j1 + 16 <= e1; j1 += 16) {
            int p0 = csr_off[j1 + q];
            int p1 = csr_off[j1 + 4 + q];
            int p2 = csr_off[j1 + 8 + q];
            int p3 = csr_off[j1 + 12 + q];
            uint2 w0 = *(const uint2*)(hb + p0 + fb);
            uint2 w1 = *(const uint2*)(hb + p1 + fb);
            uint2 w2 = *(const uint2*)(hb + p2 + fb);
            uint2 w3 = *(const uint2*)(hb + p3 + fb);
            c01 += up2(w0.x); c23 += up2(w0.y);
            c01 += up2(w1.x); c23 += up2(w1.y);
            c01 += up2(w2.x); c23 += up2(w2.y);
            c01 += up2(w3.x); c23 += up2(w3.y);
        }
        // combined guarded tail (<16 left per node; csr_off reads up to
        // NE+14 land in the allocated bufA region, values discarded)
        if (j0 < e0 || j1 < e1) {
            int i0 = j0 + q, i1 = j0 + 4 + q, i2 = j0 + 8 + q, i3 = j0 + 12 + q;
            int k0 = j1 + q, k1 = j1 + 4 + q, k2 = j1 + 8 + q, k3 = j1 + 12 + q;
            int o0 = csr_off[i0]; o0 = (i0 < e0) ? o0 : Z;
            int o1 = csr_off[i1]; o1 = (i1 < e0) ? o1 : Z;
            int o2 = csr_off[i2]; o2 = (i2 < e0) ? o2 : Z;
            int o3 = csr_off[i3]; o3 = (i3 < e0) ? o3 : Z;
            int p0 = csr_off[k0]; p0 = (k0 < e1) ? p0 : Z;
            int p1 = csr_off[k1]; p1 = (k1 < e1) ? p1 : Z;
            int p2 = csr_off[k2]; p2 = (k2 < e1) ? p2 : Z;
            int p3 = csr_off[k3]; p3 = (k3 < e1) ? p3 : Z;
            uint2 v0 = *(const uint2*)(hb + o0 + fb);
            uint2 v1 = *(const uint2*)(hb + o1 + fb);
            uint2 v2 = *(const uint2*)(hb + o2 + fb);
            uint2 v3 = *(const uint2*)(hb + o3 + fb);
            uint2 w0 = *(const uint2*)(hb + p0 + fb);
            uint2 w1 = *(const uint2*)(hb + p1 + fb);
            uint2 w2 = *(const uint2*)(hb + p2 + fb);
            uint2 w3 = *(const uint2*)(hb + p3 + fb);
            a01 += up2(v0.x); a23 += up2(v0.y);
            a01 += up2(v1.x); a23 += up2(v1.y);
            a01 += up2(v2.x); a23 += up2(v2.y);
            a01 += up2(v3.x); a23 += up2(v3.y);
            c01 += up2(w0.x); c23 += up2(w0.y);
            c01 += up2(w1.x); c23 += up2(w1.y);
            c01 += up2(w2.x); c23 += up2(w2.y);
            c01 += up2(w3.x); c23 += up2(w3.y);
        }
        // reduce across the 4 row slots (q): xor-32 then xor-16, both nodes
        float a0 = a01.x, a1 = a01.y, a2 = a23.x, a3 = a23.y;
        float c0 = c01.x, c1 = c01.y, c2 = c23.x, c3 = c23.y;
        a0 += __shfl_xor(a0, 32); a1 += __shfl_xor(a1, 32);
        a2 += __shfl_xor(a2, 32); a3 += __shfl_xor(a3, 32);
        c0 += __shfl_xor(c0, 32); c1 += __shfl_xor(c1, 32);
        c2 += __shfl_xor(c2, 32); c3 += __shfl_xor(c3, 32);
        a0 += __shfl_xor(a0, 16); a1 += __shfl_xor(a1, 16);
        a2 += __shfl_xor(a2, 16); a3 += __shfl_xor(a3, 16);
        c0 += __shfl_xor(c0, 16); c1 += __shfl_xor(c1, 16);
        c2 += __shfl_xor(c2, 16); c3 += __shfl_xor(c3, 16);
        if (q == 0) {
            uint2 sv0 = *(const uint2*)(hb + n0 * 128 + fb);  // self rows
            uint2 sv1 = *(const uint2*)(hb + n1 * 128 + fb);
            float dn0 = dis[n0], dn1 = dis[n1];
            float o0 = fmaxf(dn0 * (a0 + blo(sv0.x)) + b0, 0.f);
            float o1 = fmaxf(dn0 * (a1 + bhi(sv0.x)) + b1v, 0.f);
            float o2 = fmaxf(dn0 * (a2 + blo(sv0.y)) + b2v, 0.f);
            float o3 = fmaxf(dn0 * (a3 + bhi(sv0.y)) + b3v, 0.f);
            float u0 = fmaxf(dn1 * (c0 + blo(sv1.x)) + b0, 0.f);
            float u1 = fmaxf(dn1 * (c1 + bhi(sv1.x)) + b1v, 0.f);
            float u2 = fmaxf(dn1 * (c2 + blo(sv1.y)) + b2v, 0.f);
            float u3 = fmaxf(dn1 * (c3 + bhi(sv1.y)) + b3v, 0.f);
            if (f32) {
                float4 ov = {o0, o1, o2, o3};
                float4 uv = {u0, u1, u2, u3};
                *(float4*)((float*)hout + hoBase + n0 * 64 + m * 4) = ov;
                *(float4*)((float*)hout + hoBase + n1 * 64 + m * 4) = uv;
            } else {
                unsigned w0 = (unsigned)f2b(o0) | ((unsigned)f2b(o1) << 16);
                unsigned w1 = (unsigned)f2b(o2) | ((unsigned)f2b(o3) << 16);
                unsigned w2 = (unsigned)f2b(u0) | ((unsigned)f2b(u1) << 16);
                unsigned w3 = (unsigned)f2b(u2) | ((unsigned)f2b(u3) << 16);
                uint2 wv0; wv0.x = w0; wv0.y = w1;
                uint2 wv1; wv1.x = w2; wv1.y = w3;
                *(uint2*)((ushort*)hout + hoBase + n0 * 64 + m * 4) = wv0;
                *(uint2*)((ushort*)hout + hoBase + n1 * 64 + m * 4) = wv1;
            }
        }
    }
}

// ---------------- head: log_softmax(h2 @ W3 + b3) -------------------------
__global__ void k_head(const void* __restrict__ h2, int hBase,
                       const void* __restrict__ W3, const void* __restrict__ b3,
                       void* out, const int* __restrict__ flag) {
    __shared__ float w[64 * 16];
    __shared__ float hrow[16 * 64];
    int f32 = *flag;
    int t = threadIdx.x;
#pragma unroll
    for (int i = 0; i < 4; i++) w[t + i * 256] = ldf(W3, t + i * 256, f32);
    int r0 = blockIdx.x * 16;
#pragma unroll
    for (int i = 0; i < 4; i++) hrow[t + i * 256] = ldf(h2, hBase + r0 * 64 + t + i * 256, f32);
    __syncthreads();
    int lr = t >> 4, c = t & 15;
    float z = ldf(b3, c, f32);
#pragma unroll
    for (int k = 0; k < 64; k++) z += hrow[lr * 64 + k] * w[k * 16 + c];
    float m = z;
#pragma unroll
    for (int off = 8; off >= 1; off >>= 1) m = fmaxf(m, __shfl_xor(m, off, 16));
    float p = expf(z - m);
    float s = p;
#pragma unroll
    for (int off = 8; off >= 1; off >>= 1) s += __shfl_xor(s, off, 16);
    stf(out, (r0 + lr) * 16 + c, f32, z - m - logf(s));
}

extern "C" void kernel_launch(void* const* d_in, const int* in_sizes, int n_in,
                              void* d_out, int out_size, void* d_ws, size_t ws_size,
                              hipStream_t stream) {
    const void* x  = d_in[0];
    const int* ei  = (const int*)d_in[1];
    const void* W1 = d_in[2];
    const void* b1 = d_in[3];
    const void* W2 = d_in[4];
    const void* b2 = d_in[5];
    const void* W3 = d_in[6];
    const void* b3 = d_in[7];

    // ws layout (4B words):
    //   0       : flag (256)
    //   256     : dis (102400)
    //   102656  : rowptr (102400, NN+1 used)
    //   205568  : btot (512, NBKT used)
    //   207104  : csr_off (NE)  -- byte offsets src*128
    //   1807104 : union { [bbuf u32[NBKT*BCAP]=1801728 | cnt 153088 | prefT 153088]
    //                     (CSR build, dead before GEMM) |
    //                     bufA bf16[(NN+1)*64] = 3200032 w }
    //             bufA row NN (bytes 12.8e6..12.8e6+128) is the zero pad row.
    const size_t NEEDED = (size_t)(1807104 + 3203072) * 4;  // ~20.05 MB (unchanged)
    if (ws_size < NEEDED) {
        k_sentinel<<<1, 64, 0, stream>>>((unsigned*)d_out);
        return;
    }
    int*      flag    = (int*)d_ws;
    float*    dis     = (float*)d_ws + 256;
    int*      rowptr  = (int*)d_ws + 102656;
    int*      btot    = (int*)d_ws + 205568;
    int*      csr_off = (int*)d_ws + 207104;
    unsigned* bbuf    = (unsigned*)((int*)d_ws + 1807104);
    int*      cnt     = (int*)d_ws + 1807104 + NBKT * BCAP;          // 3608832
    int*      prefT   = cnt + 153088;                                 // 3761920
    bf16*     bufA    = (bf16*)bbuf;   // overwrites CSR scratch after pass2

    const int* srcp = ei;
    const int* dstp = ei + NE;
    const int HB = NN * 16;   // h region starts at element NN*16 of d_out

    // ---- CSR build: count+detect -> column scan -> place -> sort ----------
    k_cnt<<<NP1, 256, 0, stream>>>((const unsigned*)x, flag, dstp, cnt);
    k_colscan<<<NBKT, 512, 0, stream>>>(cnt, prefT, btot);
    k_place<<<NP1, 256, 0, stream>>>(srcp, dstp, prefT, bbuf);
    k_pass2<<<NBKT, 256, 0, stream>>>(bbuf, btot, rowptr, dis, csr_off);

    // ---- layer 1: h1 = relu(Agg(x @ W1) + b1) ----
    k_gemm_mfma<<<512, 256, 0, stream>>>(x, 0, W1, bufA, dis, flag);
    k_aggregate<<<2048, 256, 0, stream>>>(bufA, d_out, HB, dis, rowptr, csr_off, b1, flag);

    // ---- layer 2: h2 = relu(Agg(h1 @ W2) + b2) ----
    k_gemm_mfma<<<512, 256, 0, stream>>>(d_out, HB, W2, bufA, dis, flag);
    k_aggregate<<<2048, 256, 0, stream>>>(bufA, d_out, HB, dis, rowptr, csr_off, b2, flag);

    // ---- head ----
    k_head<<<NN / 16, 256, 0, stream>>>(d_out, HB, W3, b3, d_out, flag);
}

// Round 7
// 251.749 us; speedup vs baseline: 1.0142x; 1.0142x over previous
//
#include <hip/hip_runtime.h>
#include <hip/hip_bf16.h>

typedef __hip_bfloat16 bf16;
typedef unsigned short ushort;

#define NN 100000
#define NE 1600000
#define NBKT 391      // ceil(NN/256) buckets of 256 dst nodes
#define BCAP 4608     // per-bucket capacity (mean 4092, sd 64, +8 sigma)
#define EPB 4096      // edges per count/place block
#define NP1 391       // ceil(NE/EPB)
#define NMT 6250      // NN/16 M-tiles for the MFMA GEMM

typedef __attribute__((ext_vector_type(8))) short s8v;   // 8 bf16 (4 VGPRs)
typedef __attribute__((ext_vector_type(4))) float f4v;   // MFMA C/D
typedef __attribute__((ext_vector_type(2))) float f2v;   // packed f32 (v_pk_add_f32)

// ---- flag-dispatched load/store: flag==1 -> f32 storage, 0 -> bf16 -------
__device__ __forceinline__ float ldf(const void* p, int i, int f32) {
    return f32 ? ((const float*)p)[i] : __bfloat162float(((const bf16*)p)[i]);
}
__device__ __forceinline__ void stf(void* p, int i, int f32, float v) {
    if (f32) ((float*)p)[i] = v;
    else     ((bf16*)p)[i] = __float2bfloat16(v);
}

// round-to-nearest-even float -> bf16 bits, and back
__device__ __forceinline__ ushort f2b(float f) {
    unsigned u = __builtin_bit_cast(unsigned, f);
    u += 0x7FFF + ((u >> 16) & 1);
    return (ushort)(u >> 16);
}
__device__ __forceinline__ float b2f(ushort h) {
    unsigned u = ((unsigned)h) << 16;
    return __builtin_bit_cast(float, u);
}
// bf16x2 dword -> two f32 (lo = bits<<16, hi = bits&0xffff0000)
__device__ __forceinline__ float blo(unsigned u) {
    return __builtin_bit_cast(float, u << 16);
}
__device__ __forceinline__ float bhi(unsigned u) {
    return __builtin_bit_cast(float, u & 0xffff0000u);
}
// unpack bf16x2 dword into a packed f32 pair (consumed by v_pk_add_f32)
__device__ __forceinline__ f2v up2(unsigned u) {
    f2v r; r.x = blo(u); r.y = bhi(u); return r;
}

__global__ void k_sentinel(unsigned* out) {
    if (threadIdx.x == 0 && blockIdx.x == 0) out[0] = 0x461C461Cu;
}

// ---------------- CSR build A: per-block bucket counts + dtype detect ------
__global__ void k_cnt(const unsigned* __restrict__ x, int* __restrict__ flag,
                      const int* __restrict__ dst, int* __restrict__ cnt) {
    __shared__ int hist[NBKT];
    int b = blockIdx.x, t = threadIdx.x;
    for (int i = t; i < NBKT; i += 256) hist[i] = 0;
    __syncthreads();
    int e0 = b * EPB;
#pragma unroll
    for (int k = 0; k < EPB; k += 256) {
        int e = e0 + k + t;
        if (e < NE) atomicAdd(&hist[dst[e] >> 8], 1);
    }
    __syncthreads();
    for (int i = t; i < NBKT; i += 256) cnt[b * NBKT + i] = hist[i];
    if (b == 0) {
        // dtype detect on first 2048 words of x (merged launch; reuses hist)
        int c = 0;
        for (int i = t; i < 2048; i += 256) {
            unsigned e7 = (x[i] >> 8) & 0x7F;
            c += (e7 >= 60 && e7 <= 66) ? 1 : 0;
        }
        __syncthreads();
        hist[t] = c;
        __syncthreads();
        for (int s = 128; s > 0; s >>= 1) {
            if (t < s) hist[t] += hist[t + s];
            __syncthreads();
        }
        if (t == 0) *flag = (hist[0] >= 1024) ? 0 : 1;  // 1 = float32 tensors
    }
}

// ---------------- CSR build B: per-bucket scan over blocks -----------------
// Block k reads column cnt[.][k] (strided reads, L2/L3-cached), scans,
// writes exclusive prefixes COALESCED to prefT[k][.] and the bucket total.
__global__ void k_colscan(const int* __restrict__ cnt, int* __restrict__ prefT,
                          int* __restrict__ btot) {
    __shared__ int s[512];
    int k = blockIdx.x, t = threadIdx.x;
    int v = (t < NP1) ? cnt[t * NBKT + k] : 0;
    s[t] = v;
    __syncthreads();
    for (int d = 1; d < 512; d <<= 1) {
        int add = (t >= d) ? s[t - d] : 0;
        __syncthreads();
        s[t] += add;
        __syncthreads();
    }
    if (t < NP1) prefT[k * NP1 + t] = s[t] - v;   // exclusive over blocks
    if (t == 511) btot[k] = s[511];
}

// ---------------- CSR build C: deterministic place into buckets ------------
// No global atomics: slot = prefT[k][b] + LDS cursor. Writes are ~10-word
// contiguous runs per bucket (vs 16x-amplified random 4B stores in r3).
__global__ void k_place(const int* __restrict__ src, const int* __restrict__ dst,
                        const int* __restrict__ prefT, unsigned* __restrict__ bbuf) {
    __shared__ int base[NBKT];
    __shared__ int lcur[NBKT];
    int b = blockIdx.x, t = threadIdx.x;
    for (int i = t; i < NBKT; i += 256) {
        base[i] = prefT[i * NP1 + b];
        lcur[i] = 0;
    }
    __syncthreads();
    int e0 = b * EPB;
#pragma unroll
    for (int k = 0; k < EPB; k += 256) {
        int e = e0 + k + t;
        if (e < NE) {
            int d = dst[e];
            int kb = d >> 8;
            int lp = atomicAdd(&lcur[kb], 1);
            bbuf[kb * BCAP + base[kb] + lp] = ((unsigned)src[e] << 8) | (unsigned)(d & 255);
        }
    }
}

// ---------------- CSR build D: LDS counting-sort per bucket ----------------
// Emits csr_off (BYTE offsets src*128) coalesced, plus rowptr and dis.
// Bucket base g0 = sum(btot[0..b-1]) is computed locally (replaces the
// former single-block scan kernel -- one fewer launch).
__global__ void k_pass2(const unsigned* __restrict__ bbuf, const int* __restrict__ btot,
                        int* __restrict__ rowptr, float* __restrict__ dis,
                        int* __restrict__ csr_off) {
    __shared__ unsigned vals[BCAP];
    __shared__ int lout[BCAP];
    __shared__ int fh[256], fx[256], fc[256];
    int b = blockIdx.x, t = threadIdx.x;
    // ---- local bucket base: reduce btot[0..b-1] (<=2 loads/thread) ----
    int part = 0;
    for (int i = t; i < b; i += 256) part += btot[i];
    fh[t] = part;
    __syncthreads();
    for (int s = 128; s > 0; s >>= 1) {
        if (t < s) fh[t] += fh[t + s];
        __syncthreads();
    }
    int g0 = fh[0];
    int cntb = btot[b];
    if (b == 0 && t == 0) rowptr[NN] = NE;
    __syncthreads();
    const unsigned* in = bbuf + b * BCAP;
    fh[t] = 0;
    __syncthreads();
    for (int i = t; i < cntb; i += 256) {
        unsigned v = in[i];
        vals[i] = v;
        atomicAdd(&fh[v & 255], 1);
    }
    __syncthreads();
    fx[t] = fh[t];
    __syncthreads();
    for (int d = 1; d < 256; d <<= 1) {
        int add = (t >= d) ? fx[t - d] : 0;
        __syncthreads();
        fx[t] += add;
        __syncthreads();
    }
    int n = b * 256 + t;
    int ex = fx[t] - fh[t];     // exclusive within bucket
    fc[t] = ex;
    if (n < NN) {
        rowptr[n] = g0 + ex;
        dis[n] = rsqrtf(1.0f + (float)fh[t]);
    }
    __syncthreads();
    for (int i = t; i < cntb; i += 256) {
        unsigned v = vals[i];
        int p = atomicAdd(&fc[v & 255], 1);
        lout[p] = (int)((v >> 8) << 7);   // src*128 = byte offset of bf16 row
    }
    __syncthreads();
    for (int i = t; i < cntb; i += 256) csr_off[g0 + i] = lout[i];
}

// ---------------- MFMA GEMM: C[N,64] = dis[row] * (A[N,64] @ W[64,64]) ----
__global__ void __launch_bounds__(256) k_gemm_mfma(
        const void* __restrict__ A, int aBase, const void* __restrict__ W,
        bf16* __restrict__ C, const float* __restrict__ dis,
        const int* __restrict__ flag) {
    int f32 = *flag;
    int t = threadIdx.x;
    // zero pad row NN (the aggregate's ZOFF target) once per GEMM launch
    if (blockIdx.x == 0 && t < 64) ((ushort*)C)[NN * 64 + t] = 0;
    int lane = t & 63;
    int w = t >> 6;
    int m = lane & 15, q = lane >> 4;

    s8v bh[2][4], bl[2][4];
#pragma unroll
    for (int st = 0; st < 2; st++)
#pragma unroll
        for (int nt = 0; nt < 4; nt++)
#pragma unroll
            for (int j = 0; j < 8; j++) {
                int k = st * 32 + q * 8 + j;
                float wv = ldf(W, k * 64 + nt * 16 + m, f32);
                ushort h = f2b(wv);
                bh[st][nt][j] = (short)h;
                bl[st][nt][j] = (short)f2b(wv - b2f(h));
            }

    ushort* Cu = (ushort*)C;
    int gw = blockIdx.x * 4 + w;
    int nw = gridDim.x * 4;
    for (int mt = gw; mt < NMT; mt += nw) {
        int row = mt * 16 + m;
        s8v ah[2], al[2];
        if (f32) {
            const float* ap = (const float*)A + aBase + row * 64 + q * 8;
#pragma unroll
            for (int st = 0; st < 2; st++)
#pragma unroll
                for (int j = 0; j < 8; j++) {
                    float v = ap[st * 32 + j];
                    ushort h = f2b(v);
                    ah[st][j] = (short)h;
                    al[st][j] = (short)f2b(v - b2f(h));
                }
        } else {
            const short* ap = (const short*)A + aBase + row * 64 + q * 8;
            ah[0] = *(const s8v*)(ap);
            ah[1] = *(const s8v*)(ap + 32);
        }
        float dr[4];
#pragma unroll
        for (int r = 0; r < 4; r++) dr[r] = dis[mt * 16 + q * 4 + r];
#pragma unroll
        for (int nt = 0; nt < 4; nt++) {
            f4v acc = {0.f, 0.f, 0.f, 0.f};
#pragma unroll
            for (int st = 0; st < 2; st++)
                acc = __builtin_amdgcn_mfma_f32_16x16x32_bf16(ah[st], bh[st][nt], acc, 0, 0, 0);
            if (f32) {
#pragma unroll
                for (int st = 0; st < 2; st++) {
                    acc = __builtin_amdgcn_mfma_f32_16x16x32_bf16(ah[st], bl[st][nt], acc, 0, 0, 0);
                    acc = __builtin_amdgcn_mfma_f32_16x16x32_bf16(al[st], bh[st][nt], acc, 0, 0, 0);
                }
            }
            int col = nt * 16 + m;
#pragma unroll
            for (int r = 0; r < 4; r++) {
                int rr = mt * 16 + q * 4 + r;
                Cu[rr * 64 + col] = f2b(dr[r] * acc[r]);
            }
        }
    }
}

// ---------------- fused aggregate + bias + relu (+ optional head) ----------
// hs holds PRE-SCALED rows dis[s]*h[s] (bf16). One WAVE per node, persistent
// blocks (r5 structure; r6 pairing was neutral). Lanes: 4 row-slots (q) x 16
// feature-quads (m); uint2 gathers (4 features/lane, 4 rows per VMEM instr).
// MODE==1 additionally computes log_softmax(h2 @ W3 + b3) fully in-register:
// after the q-butterflies EVERY lane holds the node's a0..a3, so all 64
// lanes compute head partials (4 feats x 4 classes, class quad = q), m-sum
// via 4 shfl_xor rounds, softmax across quads via xor16/32 -- replacing the
// separate k_head kernel (saves its 19 MB of traffic + one launch).
template<int MODE>
__global__ void __launch_bounds__(256, 8) k_aggregate(
        const bf16* __restrict__ hs, void* hout, int hoBase,
        const float* __restrict__ dis,
        const int* __restrict__ rowptr,
        const int* __restrict__ csr_off,
        const void* __restrict__ bias,
        const int* __restrict__ flag,
        const void* __restrict__ W3, const void* __restrict__ b3,
        void* __restrict__ lgout) {
    __shared__ float w3s[64 * 16];     // used only when MODE==1
    int f32 = *flag;
    int t = threadIdx.x;
    int l = t & 63;
    int q = l >> 4;           // row slot 0..3 (also head class-quad)
    int m = l & 15;           // feature quad: features 4m..4m+3
    int fb = m * 8;           // byte offset of feature quad within 128B row
    const char* hb = (const char*)hs;
    float b0 = ldf(bias, m * 4 + 0, f32);
    float b1v = ldf(bias, m * 4 + 1, f32);
    float b2v = ldf(bias, m * 4 + 2, f32);
    float b3v = ldf(bias, m * 4 + 3, f32);
    float hb3[4];
    if constexpr (MODE == 1) {
        for (int i = t; i < 1024; i += 256) w3s[i] = ldf(W3, i, f32);
#pragma unroll
        for (int j2 = 0; j2 < 4; j2++) hb3[j2] = ldf(b3, q * 4 + j2, f32);
        __syncthreads();
    }
    const int Z = NN * 128;   // zero-row byte offset
    int wid = blockIdx.x * 4 + (t >> 6);
    int nwav = gridDim.x * 4;
    for (int n = wid; n < NN; n += nwav) {
        int r0 = rowptr[n], r1 = rowptr[n + 1];
        f2v a01 = {0.f, 0.f}, a23 = {0.f, 0.f};
        int j = r0;
        // full groups: 16 edges, 4 gathers, zero per-edge branching
        for (; j + 16 <= r1; j += 16) {
            int o0 = csr_off[j + q];
            int o1 = csr_off[j + 4 + q];
            int o2 = csr_off[j + 8 + q];
            int o3 = csr_off[j + 12 + q];
            uint2 v0 = *(const uint2*)(hb + o0 + fb);
            uint2 v1 = *(const uint2*)(hb + o1 + fb);
            uint2 v2 = *(const uint2*)(hb + o2 + fb);
            uint2 v3 = *(const uint2*)(hb + o3 + fb);
            a01 += up2(v0.x); a23 += up2(v0.y);
            a01 += up2(v1.x); a23 += up2(v1.y);
            a01 += up2(v2.x); a23 += up2(v2.y);
            a01 += up2(v3.x); a23 += up2(v3.y);
        }
        // tail group: dead slots redirect to the zero row (csr_off reads up
        // to NE+14 land in the allocated bufA region, values discarded)
        if (j < r1) {
            int i0 = j + q, i1 = j + 4 + q, i2 = j + 8 + q, i3 = j + 12 + q;
            int o0 = csr_off[i0]; o0 = (i0 < r1) ? o0 : Z;
            int o1 = csr_off[i1]; o1 = (i1 < r1) ? o1 : Z;
            int o2 = csr_off[i2]; o2 = (i2 < r1) ? o2 : Z;
            int o3 = csr_off[i3]; o3 = (i3 < r1) ? o3 : Z;
            uint2 v0 = *(const uint2*)(hb + o0 + fb);
            uint2 v1 = *(const uint2*)(hb + o1 + fb);
            uint2 v2 = *(const uint2*)(hb + o2 + fb);
            uint2 v3 = *(const uint2*)(hb + o3 + fb);
            a01 += up2(v0.x); a23 += up2(v0.y);
            a01 += up2(v1.x); a23 += up2(v1.y);
            a01 += up2(v2.x); a23 += up2(v2.y);
            a01 += up2(v3.x); a23 += up2(v3.y);
        }
        // reduce across the 4 row slots (q): xor-32 then xor-16
        float a0 = a01.x, a1 = a01.y, a2 = a23.x, a3 = a23.y;
        a0 += __shfl_xor(a0, 32); a1 += __shfl_xor(a1, 32);
        a2 += __shfl_xor(a2, 32); a3 += __shfl_xor(a3, 32);
        a0 += __shfl_xor(a0, 16); a1 += __shfl_xor(a1, 16);
        a2 += __shfl_xor(a2, 16); a3 += __shfl_xor(a3, 16);
        // ALL lanes finish the row (head needs every lane's o0..o3)
        uint2 sv = *(const uint2*)(hb + n * 128 + fb);   // self row (pre-scaled)
        float dn = dis[n];
        float o0 = fmaxf(dn * (a0 + blo(sv.x)) + b0, 0.f);
        float o1 = fmaxf(dn * (a1 + bhi(sv.x)) + b1v, 0.f);
        float o2 = fmaxf(dn * (a2 + blo(sv.y)) + b2v, 0.f);
        float o3 = fmaxf(dn * (a3 + bhi(sv.y)) + b3v, 0.f);
        if (q == 0) {
            if (f32) {
                float4 ov = {o0, o1, o2, o3};
                *(float4*)((float*)hout + hoBase + n * 64 + m * 4) = ov;
            } else {
                unsigned w0 = (unsigned)f2b(o0) | ((unsigned)f2b(o1) << 16);
                unsigned w1 = (unsigned)f2b(o2) | ((unsigned)f2b(o3) << 16);
                uint2 wv; wv.x = w0; wv.y = w1;
                *(uint2*)((ushort*)hout + hoBase + n * 64 + m * 4) = wv;
            }
        }
        if constexpr (MODE == 1) {
            // head partials: this lane's 4 feats (k = m*4+i) x 4 classes (q*4+j)
            float z0 = 0.f, z1 = 0.f, z2 = 0.f, z3 = 0.f;
            float oo[4] = {o0, o1, o2, o3};
#pragma unroll
            for (int i = 0; i < 4; i++) {
                float4 wv = *(const float4*)(w3s + (m * 4 + i) * 16 + q * 4);
                z0 += oo[i] * wv.x; z1 += oo[i] * wv.y;
                z2 += oo[i] * wv.z; z3 += oo[i] * wv.w;
            }
            // sum over the 16 m-lanes (bits 0-3)
#pragma unroll
            for (int msk = 1; msk <= 8; msk <<= 1) {
                z0 += __shfl_xor(z0, msk); z1 += __shfl_xor(z1, msk);
                z2 += __shfl_xor(z2, msk); z3 += __shfl_xor(z3, msk);
            }
            z0 += hb3[0]; z1 += hb3[1]; z2 += hb3[2]; z3 += hb3[3];
            // log_softmax across 16 classes (quads live on q = bits 4-5)
            float M = fmaxf(fmaxf(z0, z1), fmaxf(z2, z3));
            M = fmaxf(M, __shfl_xor(M, 16));
            M = fmaxf(M, __shfl_xor(M, 32));
            float es = expf(z0 - M) + expf(z1 - M) + expf(z2 - M) + expf(z3 - M);
            es += __shfl_xor(es, 16);
            es += __shfl_xor(es, 32);
            float ls = logf(es) + M;
            if (m == 0) {
                if (f32) {
                    float4 ov = {z0 - ls, z1 - ls, z2 - ls, z3 - ls};
                    *(float4*)((float*)lgout + n * 16 + q * 4) = ov;
                } else {
                    unsigned p0 = (unsigned)f2b(z0 - ls) | ((unsigned)f2b(z1 - ls) << 16);
                    unsigned p1 = (unsigned)f2b(z2 - ls) | ((unsigned)f2b(z3 - ls) << 16);
                    uint2 pv; pv.x = p0; pv.y = p1;
                    *(uint2*)((ushort*)lgout + n * 16 + q * 4) = pv;
                }
            }
        }
    }
}

extern "C" void kernel_launch(void* const* d_in, const int* in_sizes, int n_in,
                              void* d_out, int out_size, void* d_ws, size_t ws_size,
                              hipStream_t stream) {
    const void* x  = d_in[0];
    const int* ei  = (const int*)d_in[1];
    const void* W1 = d_in[2];
    const void* b1 = d_in[3];
    const void* W2 = d_in[4];
    const void* b2 = d_in[5];
    const void* W3 = d_in[6];
    const void* b3 = d_in[7];

    // ws layout (4B words):
    //   0       : flag (256)
    //   256     : dis (102400)
    //   102656  : rowptr (102400, NN+1 used)
    //   205568  : btot (512, NBKT used)
    //   207104  : csr_off (NE)  -- byte offsets src*128
    //   1807104 : union { [bbuf u32[NBKT*BCAP]=1801728 | cnt 153088 | prefT 153088]
    //                     (CSR build, dead before GEMM) |
    //                     bufA bf16[(NN+1)*64] = 3200032 w }
    //             bufA row NN (bytes 12.8e6..12.8e6+128) is the zero pad row.
    const size_t NEEDED = (size_t)(1807104 + 3203072) * 4;  // ~20.05 MB (unchanged)
    if (ws_size < NEEDED) {
        k_sentinel<<<1, 64, 0, stream>>>((unsigned*)d_out);
        return;
    }
    int*      flag    = (int*)d_ws;
    float*    dis     = (float*)d_ws + 256;
    int*      rowptr  = (int*)d_ws + 102656;
    int*      btot    = (int*)d_ws + 205568;
    int*      csr_off = (int*)d_ws + 207104;
    unsigned* bbuf    = (unsigned*)((int*)d_ws + 1807104);
    int*      cnt     = (int*)d_ws + 1807104 + NBKT * BCAP;          // 3608832
    int*      prefT   = cnt + 153088;                                 // 3761920
    bf16*     bufA    = (bf16*)bbuf;   // overwrites CSR scratch after pass2

    const int* srcp = ei;
    const int* dstp = ei + NE;
    const int HB = NN * 16;   // h region starts at element NN*16 of d_out

    // ---- CSR build: count+detect -> column scan -> place -> sort ----------
    k_cnt<<<NP1, 256, 0, stream>>>((const unsigned*)x, flag, dstp, cnt);
    k_colscan<<<NBKT, 512, 0, stream>>>(cnt, prefT, btot);
    k_place<<<NP1, 256, 0, stream>>>(srcp, dstp, prefT, bbuf);
    k_pass2<<<NBKT, 256, 0, stream>>>(bbuf, btot, rowptr, dis, csr_off);

    // ---- layer 1: h1 = relu(Agg(x @ W1) + b1) ----
    k_gemm_mfma<<<512, 256, 0, stream>>>(x, 0, W1, bufA, dis, flag);
    k_aggregate<0><<<2048, 256, 0, stream>>>(bufA, d_out, HB, dis, rowptr,
                                             csr_off, b1, flag,
                                             nullptr, nullptr, nullptr);

    // ---- layer 2: h2 = relu(Agg(h1 @ W2) + b2), head fused ----
    k_gemm_mfma<<<512, 256, 0, stream>>>(d_out, HB, W2, bufA, dis, flag);
    k_aggregate<1><<<2048, 256, 0, stream>>>(bufA, d_out, HB, dis, rowptr,
                                             csr_off, b2, flag,
                                             W3, b3, d_out);
}